// Round 7
// baseline (609.372 us; speedup 1.0000x reference)
//
#include <hip/hip_runtime.h>
#include <hip/hip_bf16.h>
#include <math.h>

#define B_ 8
#define N_ 625
#define D_ 128
#define H_ 8
#define HD_ 16
#define MLP_ 4096
#define SCALE_ 0.25f
#define M_ 5000

typedef __attribute__((ext_vector_type(8))) short short8;
typedef __attribute__((ext_vector_type(4))) short short4v;
typedef __attribute__((ext_vector_type(4))) float f32x4;

// ---- bf16 split helpers (RNE via bit trick; inputs finite) ----
__device__ __forceinline__ unsigned short f2bf(float f) {
    unsigned u = __float_as_uint(f);
    unsigned r = (u + 0x7FFFu + ((u >> 16) & 1u)) >> 16;
    return (unsigned short)r;
}
__device__ __forceinline__ float bf2f(unsigned short h) {
    return __uint_as_float(((unsigned)h) << 16);
}

// ---- swizzled LDS byte offsets (row-major bf16 tiles, 256B rows) ----
__device__ __forceinline__ int swz256(int row, int kbyte) {
    return row * 256 + (kbyte ^ ((row & 7) << 4));
}

// ---- async global->LDS (16B/lane, wave-uniform LDS base) ----
__device__ __forceinline__ void gll16(const void* g, void* l) {
    __builtin_amdgcn_global_load_lds((const __attribute__((address_space(1))) unsigned int*)g,
                                     (__attribute__((address_space(3))) unsigned int*)l,
                                     16, 0, 0);
}

// ---- fast exact-gelu: Abramowitz-Stegun 7.1.26 erf, |err| <= 1.5e-7 ----
__device__ __forceinline__ float gelu_fast(float v) {
    float a = fabsf(v) * 0.70710678118f;
    float t = 1.0f / (1.0f + 0.3275911f * a);
    float p = t * (0.254829592f +
              t * (-0.284496736f +
              t * (1.421413741f +
              t * (-1.453152027f +
              t * 1.061405429f))));
    float erfa = 1.0f - p * __expf(-a * a);
    float phi = 0.5f * (1.0f + copysignf(erfa, v));
    return v * phi;
}

__device__ __forceinline__ float wave_reduce_sum(float v) {
#pragma unroll
    for (int off = 32; off > 0; off >>= 1) v += __shfl_xor(v, off, 64);
    return v;
}
__device__ __forceinline__ float wave_reduce_max(float v) {
#pragma unroll
    for (int off = 32; off > 0; off >>= 1) v = fmaxf(v, __shfl_xor(v, off, 64));
    return v;
}

// ---------------- LayerNorm: one wave per row ----------------
__global__ void ln_kernel(const float* __restrict__ x, const float* __restrict__ g,
                          const float* __restrict__ b, float* __restrict__ out) {
    int wid = threadIdx.x >> 6;
    int lid = threadIdx.x & 63;
    int row = blockIdx.x * 4 + wid;
    if (row >= M_) return;
    const float* xr = x + (size_t)row * D_;
    float x0 = xr[lid], x1 = xr[lid + 64];
    float mu = wave_reduce_sum(x0 + x1) * (1.0f / D_);
    float d0 = x0 - mu, d1 = x1 - mu;
    float var = wave_reduce_sum(d0 * d0 + d1 * d1) * (1.0f / D_);
    float inv = rsqrtf(var + 1e-5f);
    float* orow = out + (size_t)row * D_;
    orow[lid]      = d0 * inv * g[lid] + b[lid];
    orow[lid + 64] = d1 * inv * g[lid + 64] + b[lid + 64];
}

// ---------------- weight transpose + bf16 hi/lo split (qkv, proj) ----------------
__global__ void tsplit(const float* __restrict__ W, unsigned short* __restrict__ Th,
                       unsigned short* __restrict__ Tl, int K, int N) {
    size_t zo = (size_t)blockIdx.z * K * N;
    __shared__ float t[32][33];
    int n0 = blockIdx.x * 32, k0 = blockIdx.y * 32;
    int c = threadIdx.x & 31, r0 = threadIdx.x >> 5;
#pragma unroll
    for (int i = 0; i < 4; i++) {
        int r = r0 + i * 8;
        t[r][c] = W[zo + (size_t)(k0 + r) * N + n0 + c];
    }
    __syncthreads();
#pragma unroll
    for (int i = 0; i < 4; i++) {
        int r = r0 + i * 8;
        float v = t[c][r];
        unsigned short h = f2bf(v);
        unsigned short l = f2bf(v - bf2f(h));
        Th[zo + (size_t)(n0 + r) * K + k0 + c] = h;
        Tl[zo + (size_t)(n0 + r) * K + k0 + c] = l;
    }
}

// ---------------- W1 prep: transpose + split + PRE-SWIZZLED k layout ----------------
__global__ void prep_w1(const float* __restrict__ W, unsigned short* __restrict__ Th,
                        unsigned short* __restrict__ Tl) {
    size_t zo = (size_t)blockIdx.z * 128 * 4096;
    size_t zo2 = (size_t)blockIdx.z * 4096 * 128;
    __shared__ float t[32][33];
    int n0 = blockIdx.x * 32, k0 = blockIdx.y * 32;
    int c = threadIdx.x & 31, r0 = threadIdx.x >> 5;
#pragma unroll
    for (int i = 0; i < 4; i++) {
        int r = r0 + i * 8;
        t[r][c] = W[zo + (size_t)(k0 + r) * 4096 + n0 + c];
    }
    __syncthreads();
#pragma unroll
    for (int i = 0; i < 4; i++) {
        int r = r0 + i * 8;
        int h = n0 + r;
        float v = t[c][r];
        unsigned short hh = f2bf(v);
        unsigned short ll = f2bf(v - bf2f(hh));
        int kk = (k0 + c) ^ ((h & 7) << 3);
        Th[zo2 + (size_t)h * 128 + kk] = hh;
        Tl[zo2 + (size_t)h * 128 + kk] = ll;
    }
}

// ---------------- W2 prep: split + kappa-permuted layout ----------------
// kappa(qh,j) = qh*4 + (j&3) + 16*(j>>2). Matches GEMM1-output A-frag k-order.
__global__ void prep_w2(const float* __restrict__ W, unsigned short* __restrict__ Th,
                        unsigned short* __restrict__ Tl) {
    size_t zo = (size_t)blockIdx.z * 4096 * 128;
    int e = blockIdx.x * 256 + threadIdx.x;
    int h = e >> 7, d = e & 127;
    float v = W[zo + (size_t)h * 128 + d];
    unsigned short hh = f2bf(v);
    unsigned short ll = f2bf(v - bf2f(hh));
    int cch = h >> 5, loc = h & 31;
    int qh = (loc & 15) >> 2;
    int j = (loc & 3) + ((loc >> 4) << 2);
    size_t off = zo + (size_t)cch * 4096 + qh * 1024 + d * 8 + j;
    Th[off] = hh;
    Tl[off] = ll;
}

// ---------------- split-bf16 MFMA GEMM: C = A(Mx128) @ B(128xNc) [+bias] [+resid] ----
template <bool BIAS, bool RESID>
__global__ __launch_bounds__(256) void gemm_mfma(
    const float* __restrict__ A, const unsigned short* __restrict__ BTh,
    const unsigned short* __restrict__ BTl, const float* __restrict__ bias,
    const float* __restrict__ resid, float* __restrict__ C, int Nc) {
    __shared__ __align__(16) char Ah[16384], Al[16384], Bh[16384], Bl[16384];
    int tid = threadIdx.x;
    int bN = blockIdx.x * 64, bM = blockIdx.y * 64;
#pragma unroll
    for (int i = 0; i < 8; i++) {
        int f = tid + i * 256;
        int row = f >> 5, k0 = (f & 31) * 4;
        int gm = bM + row;
        float4 v = make_float4(0.f, 0.f, 0.f, 0.f);
        if (gm < M_) v = *(const float4*)(A + (size_t)gm * 128 + k0);
        float vv[4] = {v.x, v.y, v.z, v.w};
        unsigned short h[4], l[4];
#pragma unroll
        for (int j = 0; j < 4; j++) { h[j] = f2bf(vv[j]); l[j] = f2bf(vv[j] - bf2f(h[j])); }
        int off = swz256(row, k0 * 2);
        *(short4v*)(Ah + off) = (short4v){(short)h[0], (short)h[1], (short)h[2], (short)h[3]};
        *(short4v*)(Al + off) = (short4v){(short)l[0], (short)l[1], (short)l[2], (short)l[3]};
    }
#pragma unroll
    for (int i = 0; i < 4; i++) {
        int c = tid + i * 256;
        int n = c >> 4, k0 = (c & 15) * 8;
        int off = swz256(n, k0 * 2);
        *(short8*)(Bh + off) = *(const short8*)(BTh + (size_t)(bN + n) * 128 + k0);
        *(short8*)(Bl + off) = *(const short8*)(BTl + (size_t)(bN + n) * 128 + k0);
    }
    __syncthreads();

    int lane = tid & 63, w = tid >> 6;
    int ln = lane & 15, qh = lane >> 4;
    int wr = w >> 1, wc = w & 1;
    f32x4 acc[2][2] = {};
#pragma unroll
    for (int ks = 0; ks < 4; ks++) {
        int kb = ks * 64 + qh * 16;
        short8 a_h[2], a_l[2], b_h[2], b_l[2];
#pragma unroll
        for (int rt = 0; rt < 2; rt++) {
            int r = wr * 32 + rt * 16 + ln;
            a_h[rt] = *(short8*)(Ah + swz256(r, kb));
            a_l[rt] = *(short8*)(Al + swz256(r, kb));
        }
#pragma unroll
        for (int ct = 0; ct < 2; ct++) {
            int n = wc * 32 + ct * 16 + ln;
            b_h[ct] = *(short8*)(Bh + swz256(n, kb));
            b_l[ct] = *(short8*)(Bl + swz256(n, kb));
        }
#pragma unroll
        for (int rt = 0; rt < 2; rt++)
#pragma unroll
            for (int ct = 0; ct < 2; ct++) {
                acc[rt][ct] = __builtin_amdgcn_mfma_f32_16x16x32_bf16(a_h[rt], b_h[ct], acc[rt][ct], 0, 0, 0);
                acc[rt][ct] = __builtin_amdgcn_mfma_f32_16x16x32_bf16(a_h[rt], b_l[ct], acc[rt][ct], 0, 0, 0);
                acc[rt][ct] = __builtin_amdgcn_mfma_f32_16x16x32_bf16(a_l[rt], b_h[ct], acc[rt][ct], 0, 0, 0);
            }
    }
#pragma unroll
    for (int rt = 0; rt < 2; rt++)
#pragma unroll
        for (int ct = 0; ct < 2; ct++) {
            int col = bN + wc * 32 + ct * 16 + ln;
            int row0 = bM + wr * 32 + rt * 16 + qh * 4;
            float bi = BIAS ? bias[col] : 0.0f;
#pragma unroll
            for (int r = 0; r < 4; r++) {
                int row = row0 + r;
                if (row < M_) {
                    float v = acc[rt][ct][r] + bi;
                    if (RESID) v += resid[(size_t)row * Nc + col];
                    C[(size_t)row * Nc + col] = v;
                }
            }
        }
}

// ---------------- attention v2: float4 LDS tiles, 4 rows/wave, XCD-affine ----------------
// grid = 2560 linear. xcd-affine decode: bh = (id%8)*8 + (id/8)/40, mt = (id/8)%40
// (blocks with equal id%8 run on one XCD -> that XCD's L2 holds 8 heads' K/V).
// 16 q-rows/block (4 waves x 4 rows). K/V chunk staged as float4 [125][9] (36-float
// row stride: bank start 4*((cc+j)%8) tiles all 32 banks; ds_read_b128 x4 per col).
// Chunk-uniform mask skip; one shared running max per wave (exact: scaling cancels).
__global__ __launch_bounds__(256, 2) void attn_lds2(const float* __restrict__ qkv,
                                                    const int* __restrict__ mask,
                                                    float* __restrict__ o) {
    __shared__ float4 Ks[125][9];
    __shared__ float4 Vs[125][9];
    int tid = threadIdx.x;
    int w = tid >> 6, lid = tid & 63;
    int id = blockIdx.x;
    int q8 = id >> 3;
    int bh = (id & 7) * 8 + q8 / 40;
    int mt = q8 % 40;
    int b = bh >> 3, h = bh & 7;

    const float* base = qkv + (size_t)b * N_ * 384;
    int row[4];
    float q[4][16];
#pragma unroll
    for (int r = 0; r < 4; r++) {
        row[r] = min(mt * 16 + w * 4 + r, N_ - 1);
        const float* qp = base + (size_t)row[r] * 384 + h * HD_;
#pragma unroll
        for (int j = 0; j < 4; j++) {
            float4 v = *(const float4*)(qp + j * 4);
            q[r][j * 4 + 0] = v.x * SCALE_;
            q[r][j * 4 + 1] = v.y * SCALE_;
            q[r][j * 4 + 2] = v.z * SCALE_;
            q[r][j * 4 + 3] = v.w * SCALE_;
        }
    }

    float m = -3.4e38f;
    float l[4] = {0.f, 0.f, 0.f, 0.f};
    float acc[4][16] = {};

    for (int ci = 0; ci < 5; ci++) {
        bool active = (ci == 4) || (mask[b * 4 + ci] != 0);  // block-uniform
        if (!active) continue;
        __syncthreads();
        const float* kc = base + 128 + h * HD_ + (size_t)ci * 125 * 384;
        const float* vc = base + 256 + h * HD_ + (size_t)ci * 125 * 384;
        for (int e = tid; e < 500; e += 256) {
            int c = e >> 2, j = e & 3;
            Ks[c][j] = *(const float4*)(kc + (size_t)c * 384 + j * 4);
            Vs[c][j] = *(const float4*)(vc + (size_t)c * 384 + j * 4);
        }
        __syncthreads();

        float s[4][2];
        float cmax = -3.4e38f;
#pragma unroll
        for (int i = 0; i < 2; i++) {
            int cc = lid + i * 64;
            if (cc < 125) {
                float4 k0 = Ks[cc][0], k1 = Ks[cc][1], k2 = Ks[cc][2], k3 = Ks[cc][3];
                float kk[16] = {k0.x, k0.y, k0.z, k0.w, k1.x, k1.y, k1.z, k1.w,
                                k2.x, k2.y, k2.z, k2.w, k3.x, k3.y, k3.z, k3.w};
#pragma unroll
                for (int r = 0; r < 4; r++) {
                    float a = 0.f;
#pragma unroll
                    for (int d = 0; d < 16; d++) a += q[r][d] * kk[d];
                    s[r][i] = a;
                    cmax = fmaxf(cmax, a);
                }
            }
        }
        cmax = wave_reduce_max(cmax);
        float mnew = fmaxf(m, cmax);
        if (mnew > m) {               // wave-uniform
            float f = __expf(m - mnew);   // first active chunk: 0, accs are 0
#pragma unroll
            for (int r = 0; r < 4; r++) {
                l[r] *= f;
#pragma unroll
                for (int d = 0; d < 16; d++) acc[r][d] *= f;
            }
            m = mnew;
        }
#pragma unroll
        for (int i = 0; i < 2; i++) {
            int cc = lid + i * 64;
            if (cc < 125) {
                float4 v0 = Vs[cc][0], v1 = Vs[cc][1], v2 = Vs[cc][2], v3 = Vs[cc][3];
                float vv[16] = {v0.x, v0.y, v0.z, v0.w, v1.x, v1.y, v1.z, v1.w,
                                v2.x, v2.y, v2.z, v2.w, v3.x, v3.y, v3.z, v3.w};
#pragma unroll
                for (int r = 0; r < 4; r++) {
                    float p = __expf(s[r][i] - m);
                    l[r] += p;
#pragma unroll
                    for (int d = 0; d < 16; d++) acc[r][d] += p * vv[d];
                }
            }
        }
    }

#pragma unroll
    for (int r = 0; r < 4; r++) l[r] = wave_reduce_sum(l[r]);
#pragma unroll
    for (int r = 0; r < 4; r++)
#pragma unroll
        for (int d = 0; d < 16; d++) acc[r][d] = wave_reduce_sum(acc[r][d]);

#pragma unroll
    for (int r = 0; r < 4; r++) {
        float ov = 0.f;
#pragma unroll
        for (int d = 0; d < 16; d++) ov = (lid == d) ? acc[r][d] : ov;
        if (lid < 16)
            o[(size_t)(b * N_ + row[r]) * D_ + h * HD_ + lid] = ov / l[r];
    }
}

// ---------------- out = resid + b2 (pre-init for MLP atomic accumulation) ----------------
__global__ void init_out(const float* __restrict__ resid, const float* __restrict__ b2,
                         float* __restrict__ dest) {
    int idx = blockIdx.x * 256 + threadIdx.x;
    if (idx < M_ * D_) dest[idx] = resid[idx] + b2[idx & 127];
}

// ---------------- fused MLP v3: reg-resident P + T3 double-buffer prefetch ----------------
__global__ __launch_bounds__(256, 2) void mlp_mfma3(
    const float* __restrict__ H2, const unsigned short* __restrict__ W1sh,
    const unsigned short* __restrict__ W1sl, const float* __restrict__ b1f,
    const unsigned short* __restrict__ W2kh, const unsigned short* __restrict__ W2kl,
    float* __restrict__ dest) {
    __shared__ __align__(16) char smem[66560];  // [0,32K) buf0, [32K,64K) buf1, [64K,+1K) b1f
    int tid = threadIdx.x;
    int slice = blockIdx.x & 15;
    int mt = blockIdx.x >> 4;
    int jb = slice * 256;
    int mbase = mt * 64;
    int lane = tid & 63, w = tid >> 6;
    int ln = lane & 15, qh = lane >> 4;

    const char* pb;
    if (w == 0)      pb = (const char*)W1sh + (size_t)jb * 256;
    else if (w == 1) pb = (const char*)W1sl + (size_t)jb * 256;
    else if (w == 2) pb = (const char*)W2kh + (size_t)slice * 65536;
    else             pb = (const char*)W2kl + (size_t)slice * 65536;

    int t = min(mbase + w * 16 + ln, M_ - 1);
    short8 hfh[4], hfl[4];
    {
        const float* hp = H2 + (size_t)t * 128 + qh * 8;
#pragma unroll
        for (int ks = 0; ks < 4; ks++) {
            float4 v0 = *(const float4*)(hp + ks * 32);
            float4 v1 = *(const float4*)(hp + ks * 32 + 4);
            float vv[8] = {v0.x, v0.y, v0.z, v0.w, v1.x, v1.y, v1.z, v1.w};
            short8 sh, sl;
#pragma unroll
            for (int j = 0; j < 8; j++) {
                unsigned short hh = f2bf(vv[j]);
                sh[j] = (short)hh;
                sl[j] = (short)f2bf(vv[j] - bf2f(hh));
            }
            hfh[ks] = sh; hfl[ks] = sl;
        }
    }

    {
        char* lb = smem + w * 8192;
#pragma unroll
        for (int c = 0; c < 8; c++) gll16(pb + c * 1024 + lane * 16, lb + c * 1024);
        ((float*)(smem + 65536))[tid] = b1f[jb + tid];
    }
    __syncthreads();

    const float* bls = (const float*)(smem + 65536);
    f32x4 acc2[8] = {};

    for (int it = 0; it < 8; it++) {
        char* buf = smem + (it & 1) * 32768;
        if (it < 7) {
            char* lb = smem + ((it + 1) & 1) * 32768 + w * 8192;
            const char* gb = pb + (size_t)(it + 1) * 8192;
#pragma unroll
            for (int c = 0; c < 8; c++) gll16(gb + c * 1024 + lane * 16, lb + c * 1024);
        }
        f32x4 p[2] = {};
#pragma unroll
        for (int ht = 0; ht < 2; ht++)
#pragma unroll
            for (int ks = 0; ks < 4; ks++) {
                int row = ht * 16 + ln;
                int kb = ks * 64 + qh * 16;
                short8 ah = *(short8*)(buf + swz256(row, kb));
                short8 al = *(short8*)(buf + 8192 + swz256(row, kb));
                p[ht] = __builtin_amdgcn_mfma_f32_16x16x32_bf16(ah, hfh[ks], p[ht], 0, 0, 0);
                p[ht] = __builtin_amdgcn_mfma_f32_16x16x32_bf16(ah, hfl[ks], p[ht], 0, 0, 0);
                p[ht] = __builtin_amdgcn_mfma_f32_16x16x32_bf16(al, hfh[ks], p[ht], 0, 0, 0);
            }
        short8 pah, pal;
#pragma unroll
        for (int ht = 0; ht < 2; ht++)
#pragma unroll
            for (int r = 0; r < 4; r++) {
                float bi = bls[it * 32 + ht * 16 + qh * 4 + r];
                float v = p[ht][r] + bi;
                float g = gelu_fast(v);
                unsigned short gh = f2bf(g);
                pah[ht * 4 + r] = (short)gh;
                pal[ht * 4 + r] = (short)f2bf(g - bf2f(gh));
            }
#pragma unroll
        for (int dt = 0; dt < 8; dt++) {
            int off = 16384 + qh * 2048 + (dt * 16 + ln) * 16;
            short8 bh = *(short8*)(buf + off);
            short8 bl = *(short8*)(buf + off + 8192);
            acc2[dt] = __builtin_amdgcn_mfma_f32_16x16x32_bf16(pah, bh, acc2[dt], 0, 0, 0);
            acc2[dt] = __builtin_amdgcn_mfma_f32_16x16x32_bf16(pah, bl, acc2[dt], 0, 0, 0);
            acc2[dt] = __builtin_amdgcn_mfma_f32_16x16x32_bf16(pal, bh, acc2[dt], 0, 0, 0);
        }
        __syncthreads();
    }

    int trow = mbase + w * 16 + qh * 4;
#pragma unroll
    for (int dt = 0; dt < 8; dt++) {
        int d = dt * 16 + ln;
#pragma unroll
        for (int r = 0; r < 4; r++) {
            int row = trow + r;
            if (row < M_) atomicAdd(dest + (size_t)row * 128 + d, acc2[dt][r]);
        }
    }
}

extern "C" void kernel_launch(void* const* d_in, const int* in_sizes, int n_in,
                              void* d_out, int out_size, void* d_ws, size_t ws_size,
                              hipStream_t stream) {
    const float* x     = (const float*)d_in[0];
    const int*   mask  = (const int*)d_in[1];
    const float* Wqkv  = (const float*)d_in[2];
    const float* Wproj = (const float*)d_in[3];
    const float* bproj = (const float*)d_in[4];
    const float* g1    = (const float*)d_in[5];
    const float* b1    = (const float*)d_in[6];
    const float* g2    = (const float*)d_in[7];
    const float* b2    = (const float*)d_in[8];
    const float* W1f   = (const float*)d_in[9];
    const float* b1f   = (const float*)d_in[10];
    const float* W2f   = (const float*)d_in[11];
    const float* b2f   = (const float*)d_in[12];
    float* out = (float*)d_out;
    float* ws = (float*)d_ws;

    float* xbuf   = ws;                 // 640000 f
    float* hbuf   = ws + 640000;
    float* qkvbuf = ws + 1280000;       // 1920000 f
    float* obuf   = ws + 3200000;       // 640000 f
    unsigned short* qh  = (unsigned short*)(ws + 3840000);
    unsigned short* ql  = qh + 3 * 384 * 128;
    unsigned short* phw = ql + 3 * 384 * 128;
    unsigned short* plw = phw + 3 * 128 * 128;
    unsigned short* w1h = plw + 3 * 128 * 128;   // pre-swizzled [h][k]
    unsigned short* w1l = w1h + 3 * 4096 * 128;
    unsigned short* w2h = w1l + 3 * 4096 * 128;  // kappa layout [c][qh][d][j]
    unsigned short* w2l = w2h + 3 * 128 * 4096;

    tsplit<<<dim3(12, 4, 3), 256, 0, stream>>>(Wqkv, qh, ql, 128, 384);
    tsplit<<<dim3(4, 4, 3), 256, 0, stream>>>(Wproj, phw, plw, 128, 128);
    prep_w1<<<dim3(128, 4, 3), 256, 0, stream>>>(W1f, w1h, w1l);
    prep_w2<<<dim3(2048, 1, 3), 256, 0, stream>>>(W2f, w2h, w2l);

    for (int l = 0; l < 3; l++) {
        const float* xcur = (l == 0) ? x : xbuf;
        ln_kernel<<<1250, 256, 0, stream>>>(xcur, g1 + l * D_, b1 + l * D_, hbuf);
        gemm_mfma<false, false><<<dim3(6, 79), 256, 0, stream>>>(
            hbuf, qh + (size_t)l * 384 * 128, ql + (size_t)l * 384 * 128,
            nullptr, nullptr, qkvbuf, 384);
        attn_lds2<<<2560, 256, 0, stream>>>(qkvbuf, mask, obuf);
        gemm_mfma<true, true><<<dim3(2, 79), 256, 0, stream>>>(
            obuf, phw + (size_t)l * 128 * 128, plw + (size_t)l * 128 * 128,
            bproj + l * D_, xcur, xbuf, 128);
        ln_kernel<<<1250, 256, 0, stream>>>(xbuf, g2 + l * D_, b2 + l * D_, hbuf);
        float* dest = (l == 2) ? out : xbuf;
        init_out<<<2500, 256, 0, stream>>>(xbuf, b2f + l * D_, dest);
        mlp_mfma3<<<1264, 256, 0, stream>>>(
            hbuf, w1h + (size_t)l * 4096 * 128, w1l + (size_t)l * 4096 * 128,
            b1f + (size_t)l * MLP_,
            w2h + (size_t)l * 128 * 4096, w2l + (size_t)l * 128 * 4096, dest);
    }
}

// Round 8
// 554.030 us; speedup vs baseline: 1.0999x; 1.0999x over previous
//
#include <hip/hip_runtime.h>
#include <hip/hip_bf16.h>
#include <math.h>

#define B_ 8
#define N_ 625
#define D_ 128
#define H_ 8
#define HD_ 16
#define MLP_ 4096
#define SCALE_ 0.25f
#define M_ 5000

typedef __attribute__((ext_vector_type(8))) short short8;
typedef __attribute__((ext_vector_type(4))) short short4v;
typedef __attribute__((ext_vector_type(4))) float f32x4;

// ---- bf16 split helpers (RNE via bit trick; inputs finite) ----
__device__ __forceinline__ unsigned short f2bf(float f) {
    unsigned u = __float_as_uint(f);
    unsigned r = (u + 0x7FFFu + ((u >> 16) & 1u)) >> 16;
    return (unsigned short)r;
}
__device__ __forceinline__ float bf2f(unsigned short h) {
    return __uint_as_float(((unsigned)h) << 16);
}

// ---- swizzled LDS byte offsets (row-major bf16 tiles, 256B rows) ----
__device__ __forceinline__ int swz256(int row, int kbyte) {
    return row * 256 + (kbyte ^ ((row & 7) << 4));
}

// ---- async global->LDS (16B/lane, wave-uniform LDS base) ----
__device__ __forceinline__ void gll16(const void* g, void* l) {
    __builtin_amdgcn_global_load_lds((const __attribute__((address_space(1))) unsigned int*)g,
                                     (__attribute__((address_space(3))) unsigned int*)l,
                                     16, 0, 0);
}

// ---- fast exact-gelu: Abramowitz-Stegun 7.1.26 erf, |err| <= 1.5e-7 ----
__device__ __forceinline__ float gelu_fast(float v) {
    float a = fabsf(v) * 0.70710678118f;
    float t = 1.0f / (1.0f + 0.3275911f * a);
    float p = t * (0.254829592f +
              t * (-0.284496736f +
              t * (1.421413741f +
              t * (-1.453152027f +
              t * 1.061405429f))));
    float erfa = 1.0f - p * __expf(-a * a);
    float phi = 0.5f * (1.0f + copysignf(erfa, v));
    return v * phi;
}

__device__ __forceinline__ float wave_reduce_sum(float v) {
#pragma unroll
    for (int off = 32; off > 0; off >>= 1) v += __shfl_xor(v, off, 64);
    return v;
}
__device__ __forceinline__ float wave_reduce_max(float v) {
#pragma unroll
    for (int off = 32; off > 0; off >>= 1) v = fmaxf(v, __shfl_xor(v, off, 64));
    return v;
}

// ---------------- LayerNorm: one wave per row ----------------
__global__ void ln_kernel(const float* __restrict__ x, const float* __restrict__ g,
                          const float* __restrict__ b, float* __restrict__ out) {
    int wid = threadIdx.x >> 6;
    int lid = threadIdx.x & 63;
    int row = blockIdx.x * 4 + wid;
    if (row >= M_) return;
    const float* xr = x + (size_t)row * D_;
    float x0 = xr[lid], x1 = xr[lid + 64];
    float mu = wave_reduce_sum(x0 + x1) * (1.0f / D_);
    float d0 = x0 - mu, d1 = x1 - mu;
    float var = wave_reduce_sum(d0 * d0 + d1 * d1) * (1.0f / D_);
    float inv = rsqrtf(var + 1e-5f);
    float* orow = out + (size_t)row * D_;
    orow[lid]      = d0 * inv * g[lid] + b[lid];
    orow[lid + 64] = d1 * inv * g[lid + 64] + b[lid + 64];
}

// ---------------- weight transpose + bf16 hi/lo split (qkv, proj) ----------------
__global__ void tsplit(const float* __restrict__ W, unsigned short* __restrict__ Th,
                       unsigned short* __restrict__ Tl, int K, int N) {
    size_t zo = (size_t)blockIdx.z * K * N;
    __shared__ float t[32][33];
    int n0 = blockIdx.x * 32, k0 = blockIdx.y * 32;
    int c = threadIdx.x & 31, r0 = threadIdx.x >> 5;
#pragma unroll
    for (int i = 0; i < 4; i++) {
        int r = r0 + i * 8;
        t[r][c] = W[zo + (size_t)(k0 + r) * N + n0 + c];
    }
    __syncthreads();
#pragma unroll
    for (int i = 0; i < 4; i++) {
        int r = r0 + i * 8;
        float v = t[c][r];
        unsigned short h = f2bf(v);
        unsigned short l = f2bf(v - bf2f(h));
        Th[zo + (size_t)(n0 + r) * K + k0 + c] = h;
        Tl[zo + (size_t)(n0 + r) * K + k0 + c] = l;
    }
}

// ---------------- W1 prep: transpose + split + PRE-SWIZZLED k layout ----------------
__global__ void prep_w1(const float* __restrict__ W, unsigned short* __restrict__ Th,
                        unsigned short* __restrict__ Tl) {
    size_t zo = (size_t)blockIdx.z * 128 * 4096;
    size_t zo2 = (size_t)blockIdx.z * 4096 * 128;
    __shared__ float t[32][33];
    int n0 = blockIdx.x * 32, k0 = blockIdx.y * 32;
    int c = threadIdx.x & 31, r0 = threadIdx.x >> 5;
#pragma unroll
    for (int i = 0; i < 4; i++) {
        int r = r0 + i * 8;
        t[r][c] = W[zo + (size_t)(k0 + r) * 4096 + n0 + c];
    }
    __syncthreads();
#pragma unroll
    for (int i = 0; i < 4; i++) {
        int r = r0 + i * 8;
        int h = n0 + r;
        float v = t[c][r];
        unsigned short hh = f2bf(v);
        unsigned short ll = f2bf(v - bf2f(hh));
        int kk = (k0 + c) ^ ((h & 7) << 3);
        Th[zo2 + (size_t)h * 128 + kk] = hh;
        Tl[zo2 + (size_t)h * 128 + kk] = ll;
    }
}

// ---------------- W2 prep: split + kappa-permuted layout ----------------
// kappa(qh,j) = qh*4 + (j&3) + 16*(j>>2). Matches GEMM1-output A-frag k-order.
__global__ void prep_w2(const float* __restrict__ W, unsigned short* __restrict__ Th,
                        unsigned short* __restrict__ Tl) {
    size_t zo = (size_t)blockIdx.z * 4096 * 128;
    int e = blockIdx.x * 256 + threadIdx.x;
    int h = e >> 7, d = e & 127;
    float v = W[zo + (size_t)h * 128 + d];
    unsigned short hh = f2bf(v);
    unsigned short ll = f2bf(v - bf2f(hh));
    int cch = h >> 5, loc = h & 31;
    int qh = (loc & 15) >> 2;
    int j = (loc & 3) + ((loc >> 4) << 2);
    size_t off = zo + (size_t)cch * 4096 + qh * 1024 + d * 8 + j;
    Th[off] = hh;
    Tl[off] = ll;
}

// ---------------- split-bf16 MFMA GEMM: C = A(Mx128) @ B(128xNc) [+bias] [+resid] ----
template <bool BIAS, bool RESID>
__global__ __launch_bounds__(256) void gemm_mfma(
    const float* __restrict__ A, const unsigned short* __restrict__ BTh,
    const unsigned short* __restrict__ BTl, const float* __restrict__ bias,
    const float* __restrict__ resid, float* __restrict__ C, int Nc) {
    __shared__ __align__(16) char Ah[16384], Al[16384], Bh[16384], Bl[16384];
    int tid = threadIdx.x;
    int bN = blockIdx.x * 64, bM = blockIdx.y * 64;
#pragma unroll
    for (int i = 0; i < 8; i++) {
        int f = tid + i * 256;
        int row = f >> 5, k0 = (f & 31) * 4;
        int gm = bM + row;
        float4 v = make_float4(0.f, 0.f, 0.f, 0.f);
        if (gm < M_) v = *(const float4*)(A + (size_t)gm * 128 + k0);
        float vv[4] = {v.x, v.y, v.z, v.w};
        unsigned short h[4], l[4];
#pragma unroll
        for (int j = 0; j < 4; j++) { h[j] = f2bf(vv[j]); l[j] = f2bf(vv[j] - bf2f(h[j])); }
        int off = swz256(row, k0 * 2);
        *(short4v*)(Ah + off) = (short4v){(short)h[0], (short)h[1], (short)h[2], (short)h[3]};
        *(short4v*)(Al + off) = (short4v){(short)l[0], (short)l[1], (short)l[2], (short)l[3]};
    }
#pragma unroll
    for (int i = 0; i < 4; i++) {
        int c = tid + i * 256;
        int n = c >> 4, k0 = (c & 15) * 8;
        int off = swz256(n, k0 * 2);
        *(short8*)(Bh + off) = *(const short8*)(BTh + (size_t)(bN + n) * 128 + k0);
        *(short8*)(Bl + off) = *(const short8*)(BTl + (size_t)(bN + n) * 128 + k0);
    }
    __syncthreads();

    int lane = tid & 63, w = tid >> 6;
    int ln = lane & 15, qh = lane >> 4;
    int wr = w >> 1, wc = w & 1;
    f32x4 acc[2][2] = {};
#pragma unroll
    for (int ks = 0; ks < 4; ks++) {
        int kb = ks * 64 + qh * 16;
        short8 a_h[2], a_l[2], b_h[2], b_l[2];
#pragma unroll
        for (int rt = 0; rt < 2; rt++) {
            int r = wr * 32 + rt * 16 + ln;
            a_h[rt] = *(short8*)(Ah + swz256(r, kb));
            a_l[rt] = *(short8*)(Al + swz256(r, kb));
        }
#pragma unroll
        for (int ct = 0; ct < 2; ct++) {
            int n = wc * 32 + ct * 16 + ln;
            b_h[ct] = *(short8*)(Bh + swz256(n, kb));
            b_l[ct] = *(short8*)(Bl + swz256(n, kb));
        }
#pragma unroll
        for (int rt = 0; rt < 2; rt++)
#pragma unroll
            for (int ct = 0; ct < 2; ct++) {
                acc[rt][ct] = __builtin_amdgcn_mfma_f32_16x16x32_bf16(a_h[rt], b_h[ct], acc[rt][ct], 0, 0, 0);
                acc[rt][ct] = __builtin_amdgcn_mfma_f32_16x16x32_bf16(a_h[rt], b_l[ct], acc[rt][ct], 0, 0, 0);
                acc[rt][ct] = __builtin_amdgcn_mfma_f32_16x16x32_bf16(a_l[rt], b_h[ct], acc[rt][ct], 0, 0, 0);
            }
    }
#pragma unroll
    for (int rt = 0; rt < 2; rt++)
#pragma unroll
        for (int ct = 0; ct < 2; ct++) {
            int col = bN + wc * 32 + ct * 16 + ln;
            int row0 = bM + wr * 32 + rt * 16 + qh * 4;
            float bi = BIAS ? bias[col] : 0.0f;
#pragma unroll
            for (int r = 0; r < 4; r++) {
                int row = row0 + r;
                if (row < M_) {
                    float v = acc[rt][ct][r] + bi;
                    if (RESID) v += resid[(size_t)row * Nc + col];
                    C[(size_t)row * Nc + col] = v;
                }
            }
        }
}

// ---------------- attention v3: round-6 structure + float4 (b128) K/V reads ----------------
// grid (79, 64): blockIdx.y = b*8+h, 8-row tile, 4 waves, 2 rows/wave (56-VGPR regime).
// K/V staged [125][20] floats (80B rows, 16B aligned); float4 reads: slot = cc*5+j,
// 5 coprime 8 -> 8 consecutive lanes cover all 32 banks -> conflict-free ds_read_b128.
// Chunk-uniform mask skip; shared running max per wave (exact: scaling cancels).
__global__ __launch_bounds__(256) void attn_lds3(const float* __restrict__ qkv,
                                                 const int* __restrict__ mask,
                                                 float* __restrict__ o) {
    __shared__ float Ks[125][20];
    __shared__ float Vs[125][20];
    int tid = threadIdx.x;
    int wid = tid >> 6, lid = tid & 63;
    int bh = blockIdx.y;
    int b = bh >> 3, h = bh & 7;
    int row0 = blockIdx.x * 8 + wid * 2;

    const float* base = qkv + (size_t)b * N_ * 384;
    int r0 = min(row0, N_ - 1), r1 = min(row0 + 1, N_ - 1);
    const float* qp0 = base + (size_t)r0 * 384 + h * HD_;
    const float* qp1 = base + (size_t)r1 * 384 + h * HD_;
    float q0[16], q1[16];
#pragma unroll
    for (int j = 0; j < 4; j++) {
        float4 v0 = *(const float4*)(qp0 + j * 4);
        float4 v1 = *(const float4*)(qp1 + j * 4);
        q0[j * 4 + 0] = v0.x * SCALE_; q0[j * 4 + 1] = v0.y * SCALE_;
        q0[j * 4 + 2] = v0.z * SCALE_; q0[j * 4 + 3] = v0.w * SCALE_;
        q1[j * 4 + 0] = v1.x * SCALE_; q1[j * 4 + 1] = v1.y * SCALE_;
        q1[j * 4 + 2] = v1.z * SCALE_; q1[j * 4 + 3] = v1.w * SCALE_;
    }

    float m = -3.4e38f, l0 = 0.f, l1 = 0.f;
    float acc0[16] = {}, acc1[16] = {};

    for (int ci = 0; ci < 5; ci++) {
        bool active = (ci == 4) || (mask[b * 4 + ci] != 0);  // block-uniform
        if (!active) continue;
        __syncthreads();   // prior chunk's LDS readers done
        const float* kc = base + 128 + h * HD_ + (size_t)ci * 125 * 384;
        const float* vc = base + 256 + h * HD_ + (size_t)ci * 125 * 384;
        for (int e = tid; e < 500; e += 256) {
            int c = e >> 2, d4 = (e & 3) * 4;
            *(float4*)&Ks[c][d4] = *(const float4*)(kc + (size_t)c * 384 + d4);
            *(float4*)&Vs[c][d4] = *(const float4*)(vc + (size_t)c * 384 + d4);
        }
        __syncthreads();

        float s0[2], s1[2];
        float cmax = -3.4e38f;
#pragma unroll
        for (int i = 0; i < 2; i++) {
            int cc = lid + i * 64;
            if (cc < 125) {
                const float4* kp = (const float4*)&Ks[cc][0];
                float4 k0 = kp[0], k1 = kp[1], k2 = kp[2], k3 = kp[3];
                float kk[16] = {k0.x, k0.y, k0.z, k0.w, k1.x, k1.y, k1.z, k1.w,
                                k2.x, k2.y, k2.z, k2.w, k3.x, k3.y, k3.z, k3.w};
                float a0 = 0.f, a1 = 0.f;
#pragma unroll
                for (int d = 0; d < 16; d++) {
                    a0 += q0[d] * kk[d];
                    a1 += q1[d] * kk[d];
                }
                s0[i] = a0; s1[i] = a1;
                cmax = fmaxf(cmax, fmaxf(a0, a1));
            }
        }
        cmax = wave_reduce_max(cmax);
        float mnew = fmaxf(m, cmax);
        if (mnew > m) {               // wave-uniform; skipped when max doesn't grow
            float f = __expf(m - mnew);   // first chunk: exp(-huge)=0, accs are 0
            l0 *= f; l1 *= f;
#pragma unroll
            for (int d = 0; d < 16; d++) { acc0[d] *= f; acc1[d] *= f; }
            m = mnew;
        }
#pragma unroll
        for (int i = 0; i < 2; i++) {
            int cc = lid + i * 64;
            if (cc < 125) {
                const float4* vp = (const float4*)&Vs[cc][0];
                float4 v0 = vp[0], v1 = vp[1], v2 = vp[2], v3 = vp[3];
                float vv[16] = {v0.x, v0.y, v0.z, v0.w, v1.x, v1.y, v1.z, v1.w,
                                v2.x, v2.y, v2.z, v2.w, v3.x, v3.y, v3.z, v3.w};
                float p0 = __expf(s0[i] - m), p1 = __expf(s1[i] - m);
                l0 += p0; l1 += p1;
#pragma unroll
                for (int d = 0; d < 16; d++) {
                    acc0[d] += p0 * vv[d];
                    acc1[d] += p1 * vv[d];
                }
            }
        }
    }

    l0 = wave_reduce_sum(l0); l1 = wave_reduce_sum(l1);
#pragma unroll
    for (int d = 0; d < 16; d++) {
        acc0[d] = wave_reduce_sum(acc0[d]);
        acc1[d] = wave_reduce_sum(acc1[d]);
    }
    float o0 = 0.f, o1 = 0.f;
#pragma unroll
    for (int d = 0; d < 16; d++) {
        o0 = (lid == d) ? acc0[d] : o0;
        o1 = (lid == d) ? acc1[d] : o1;
    }
    if (lid < 16) {
        if (row0 < N_)     o[(size_t)(b * N_ + row0) * D_ + h * HD_ + lid]     = o0 / l0;
        if (row0 + 1 < N_) o[(size_t)(b * N_ + row0 + 1) * D_ + h * HD_ + lid] = o1 / l1;
    }
}

// ---------------- out = resid + b2 (pre-init for MLP atomic accumulation) ----------------
__global__ void init_out(const float* __restrict__ resid, const float* __restrict__ b2,
                         float* __restrict__ dest) {
    int idx = blockIdx.x * 256 + threadIdx.x;
    if (idx < M_ * D_) dest[idx] = resid[idx] + b2[idx & 127];
}

// ---------------- fused MLP v3: reg-resident P + T3 double-buffer prefetch ----------------
__global__ __launch_bounds__(256, 2) void mlp_mfma3(
    const float* __restrict__ H2, const unsigned short* __restrict__ W1sh,
    const unsigned short* __restrict__ W1sl, const float* __restrict__ b1f,
    const unsigned short* __restrict__ W2kh, const unsigned short* __restrict__ W2kl,
    float* __restrict__ dest) {
    __shared__ __align__(16) char smem[66560];  // [0,32K) buf0, [32K,64K) buf1, [64K,+1K) b1f
    int tid = threadIdx.x;
    int slice = blockIdx.x & 15;
    int mt = blockIdx.x >> 4;
    int jb = slice * 256;
    int mbase = mt * 64;
    int lane = tid & 63, w = tid >> 6;
    int ln = lane & 15, qh = lane >> 4;

    const char* pb;
    if (w == 0)      pb = (const char*)W1sh + (size_t)jb * 256;
    else if (w == 1) pb = (const char*)W1sl + (size_t)jb * 256;
    else if (w == 2) pb = (const char*)W2kh + (size_t)slice * 65536;
    else             pb = (const char*)W2kl + (size_t)slice * 65536;

    int t = min(mbase + w * 16 + ln, M_ - 1);
    short8 hfh[4], hfl[4];
    {
        const float* hp = H2 + (size_t)t * 128 + qh * 8;
#pragma unroll
        for (int ks = 0; ks < 4; ks++) {
            float4 v0 = *(const float4*)(hp + ks * 32);
            float4 v1 = *(const float4*)(hp + ks * 32 + 4);
            float vv[8] = {v0.x, v0.y, v0.z, v0.w, v1.x, v1.y, v1.z, v1.w};
            short8 sh, sl;
#pragma unroll
            for (int j = 0; j < 8; j++) {
                unsigned short hh = f2bf(vv[j]);
                sh[j] = (short)hh;
                sl[j] = (short)f2bf(vv[j] - bf2f(hh));
            }
            hfh[ks] = sh; hfl[ks] = sl;
        }
    }

    {
        char* lb = smem + w * 8192;
#pragma unroll
        for (int c = 0; c < 8; c++) gll16(pb + c * 1024 + lane * 16, lb + c * 1024);
        ((float*)(smem + 65536))[tid] = b1f[jb + tid];
    }
    __syncthreads();

    const float* bls = (const float*)(smem + 65536);
    f32x4 acc2[8] = {};

    for (int it = 0; it < 8; it++) {
        char* buf = smem + (it & 1) * 32768;
        if (it < 7) {
            char* lb = smem + ((it + 1) & 1) * 32768 + w * 8192;
            const char* gb = pb + (size_t)(it + 1) * 8192;
#pragma unroll
            for (int c = 0; c < 8; c++) gll16(gb + c * 1024 + lane * 16, lb + c * 1024);
        }
        f32x4 p[2] = {};
#pragma unroll
        for (int ht = 0; ht < 2; ht++)
#pragma unroll
            for (int ks = 0; ks < 4; ks++) {
                int row = ht * 16 + ln;
                int kb = ks * 64 + qh * 16;
                short8 ah = *(short8*)(buf + swz256(row, kb));
                short8 al = *(short8*)(buf + 8192 + swz256(row, kb));
                p[ht] = __builtin_amdgcn_mfma_f32_16x16x32_bf16(ah, hfh[ks], p[ht], 0, 0, 0);
                p[ht] = __builtin_amdgcn_mfma_f32_16x16x32_bf16(ah, hfl[ks], p[ht], 0, 0, 0);
                p[ht] = __builtin_amdgcn_mfma_f32_16x16x32_bf16(al, hfh[ks], p[ht], 0, 0, 0);
            }
        short8 pah, pal;
#pragma unroll
        for (int ht = 0; ht < 2; ht++)
#pragma unroll
            for (int r = 0; r < 4; r++) {
                float bi = bls[it * 32 + ht * 16 + qh * 4 + r];
                float v = p[ht][r] + bi;
                float g = gelu_fast(v);
                unsigned short gh = f2bf(g);
                pah[ht * 4 + r] = (short)gh;
                pal[ht * 4 + r] = (short)f2bf(g - bf2f(gh));
            }
#pragma unroll
        for (int dt = 0; dt < 8; dt++) {
            int off = 16384 + qh * 2048 + (dt * 16 + ln) * 16;
            short8 bh = *(short8*)(buf + off);
            short8 bl = *(short8*)(buf + off + 8192);
            acc2[dt] = __builtin_amdgcn_mfma_f32_16x16x32_bf16(pah, bh, acc2[dt], 0, 0, 0);
            acc2[dt] = __builtin_amdgcn_mfma_f32_16x16x32_bf16(pah, bl, acc2[dt], 0, 0, 0);
            acc2[dt] = __builtin_amdgcn_mfma_f32_16x16x32_bf16(pal, bh, acc2[dt], 0, 0, 0);
        }
        __syncthreads();
    }

    int trow = mbase + w * 16 + qh * 4;
#pragma unroll
    for (int dt = 0; dt < 8; dt++) {
        int d = dt * 16 + ln;
#pragma unroll
        for (int r = 0; r < 4; r++) {
            int row = trow + r;
            if (row < M_) atomicAdd(dest + (size_t)row * 128 + d, acc2[dt][r]);
        }
    }
}

extern "C" void kernel_launch(void* const* d_in, const int* in_sizes, int n_in,
                              void* d_out, int out_size, void* d_ws, size_t ws_size,
                              hipStream_t stream) {
    const float* x     = (const float*)d_in[0];
    const int*   mask  = (const int*)d_in[1];
    const float* Wqkv  = (const float*)d_in[2];
    const float* Wproj = (const float*)d_in[3];
    const float* bproj = (const float*)d_in[4];
    const float* g1    = (const float*)d_in[5];
    const float* b1    = (const float*)d_in[6];
    const float* g2    = (const float*)d_in[7];
    const float* b2    = (const float*)d_in[8];
    const float* W1f   = (const float*)d_in[9];
    const float* b1f   = (const float*)d_in[10];
    const float* W2f   = (const float*)d_in[11];
    const float* b2f   = (const float*)d_in[12];
    float* out = (float*)d_out;
    float* ws = (float*)d_ws;

    float* xbuf   = ws;                 // 640000 f
    float* hbuf   = ws + 640000;
    float* qkvbuf = ws + 1280000;       // 1920000 f
    float* obuf   = ws + 3200000;       // 640000 f
    unsigned short* qh  = (unsigned short*)(ws + 3840000);
    unsigned short* ql  = qh + 3 * 384 * 128;
    unsigned short* phw = ql + 3 * 384 * 128;
    unsigned short* plw = phw + 3 * 128 * 128;
    unsigned short* w1h = plw + 3 * 128 * 128;   // pre-swizzled [h][k]
    unsigned short* w1l = w1h + 3 * 4096 * 128;
    unsigned short* w2h = w1l + 3 * 4096 * 128;  // kappa layout [c][qh][d][j]
    unsigned short* w2l = w2h + 3 * 128 * 4096;

    tsplit<<<dim3(12, 4, 3), 256, 0, stream>>>(Wqkv, qh, ql, 128, 384);
    tsplit<<<dim3(4, 4, 3), 256, 0, stream>>>(Wproj, phw, plw, 128, 128);
    prep_w1<<<dim3(128, 4, 3), 256, 0, stream>>>(W1f, w1h, w1l);
    prep_w2<<<dim3(2048, 1, 3), 256, 0, stream>>>(W2f, w2h, w2l);

    for (int l = 0; l < 3; l++) {
        const float* xcur = (l == 0) ? x : xbuf;
        ln_kernel<<<1250, 256, 0, stream>>>(xcur, g1 + l * D_, b1 + l * D_, hbuf);
        gemm_mfma<false, false><<<dim3(6, 79), 256, 0, stream>>>(
            hbuf, qh + (size_t)l * 384 * 128, ql + (size_t)l * 384 * 128,
            nullptr, nullptr, qkvbuf, 384);
        attn_lds3<<<dim3(79, 64), 256, 0, stream>>>(qkvbuf, mask, obuf);
        gemm_mfma<true, true><<<dim3(2, 79), 256, 0, stream>>>(
            obuf, phw + (size_t)l * 128 * 128, plw + (size_t)l * 128 * 128,
            bproj + l * D_, xcur, xbuf, 128);
        ln_kernel<<<1250, 256, 0, stream>>>(xbuf, g2 + l * D_, b2 + l * D_, hbuf);
        float* dest = (l == 2) ? out : xbuf;
        init_out<<<2500, 256, 0, stream>>>(xbuf, b2f + l * D_, dest);
        mlp_mfma3<<<1264, 256, 0, stream>>>(
            hbuf, w1h + (size_t)l * 4096 * 128, w1l + (size_t)l * 4096 * 128,
            b1f + (size_t)l * MLP_,
            w2h + (size_t)l * 128 * 4096, w2l + (size_t)l * 128 * 4096, dest);
    }
}

// Round 9
// 417.160 us; speedup vs baseline: 1.4608x; 1.3281x over previous
//
#include <hip/hip_runtime.h>
#include <hip/hip_bf16.h>
#include <math.h>

#define B_ 8
#define N_ 625
#define D_ 128
#define H_ 8
#define HD_ 16
#define MLP_ 4096
#define SCALE_ 0.25f
#define M_ 5000

typedef __attribute__((ext_vector_type(8))) short short8;
typedef __attribute__((ext_vector_type(4))) short short4v;
typedef __attribute__((ext_vector_type(4))) float f32x4;

// ---- bf16 split helpers (RNE via bit trick; inputs finite) ----
__device__ __forceinline__ unsigned short f2bf(float f) {
    unsigned u = __float_as_uint(f);
    unsigned r = (u + 0x7FFFu + ((u >> 16) & 1u)) >> 16;
    return (unsigned short)r;
}
__device__ __forceinline__ float bf2f(unsigned short h) {
    return __uint_as_float(((unsigned)h) << 16);
}

// ---- swizzled LDS byte offsets (row-major bf16 tiles, 256B rows) ----
__device__ __forceinline__ int swz256(int row, int kbyte) {
    return row * 256 + (kbyte ^ ((row & 7) << 4));
}

// ---- async global->LDS (16B/lane, wave-uniform LDS base) ----
__device__ __forceinline__ void gll16(const void* g, void* l) {
    __builtin_amdgcn_global_load_lds((const __attribute__((address_space(1))) unsigned int*)g,
                                     (__attribute__((address_space(3))) unsigned int*)l,
                                     16, 0, 0);
}

// ---- fast exact-gelu: Abramowitz-Stegun 7.1.26 erf, |err| <= 1.5e-7 ----
__device__ __forceinline__ float gelu_fast(float v) {
    float a = fabsf(v) * 0.70710678118f;
    float t = 1.0f / (1.0f + 0.3275911f * a);
    float p = t * (0.254829592f +
              t * (-0.284496736f +
              t * (1.421413741f +
              t * (-1.453152027f +
              t * 1.061405429f))));
    float erfa = 1.0f - p * __expf(-a * a);
    float phi = 0.5f * (1.0f + copysignf(erfa, v));
    return v * phi;
}

__device__ __forceinline__ float wave_reduce_sum(float v) {
#pragma unroll
    for (int off = 32; off > 0; off >>= 1) v += __shfl_xor(v, off, 64);
    return v;
}

// unpack 4 u32 (hi<<16 | lo bf16 pairs) into [hi|lo] and [hi|hi] short8 operands
__device__ __forceinline__ void unpack_fd(uint4 wv, short8* full, short8* dup) {
    short h0 = (short)(wv.x >> 16), h1 = (short)(wv.y >> 16),
          h2 = (short)(wv.z >> 16), h3 = (short)(wv.w >> 16);
    short l0 = (short)(wv.x & 0xffff), l1 = (short)(wv.y & 0xffff),
          l2 = (short)(wv.z & 0xffff), l3 = (short)(wv.w & 0xffff);
    *full = (short8){h0, h1, h2, h3, l0, l1, l2, l3};
    *dup  = (short8){h0, h1, h2, h3, h0, h1, h2, h3};
}

// ---------------- LayerNorm: one wave per row ----------------
__global__ void ln_kernel(const float* __restrict__ x, const float* __restrict__ g,
                          const float* __restrict__ b, float* __restrict__ out) {
    int wid = threadIdx.x >> 6;
    int lid = threadIdx.x & 63;
    int row = blockIdx.x * 4 + wid;
    if (row >= M_) return;
    const float* xr = x + (size_t)row * D_;
    float x0 = xr[lid], x1 = xr[lid + 64];
    float mu = wave_reduce_sum(x0 + x1) * (1.0f / D_);
    float d0 = x0 - mu, d1 = x1 - mu;
    float var = wave_reduce_sum(d0 * d0 + d1 * d1) * (1.0f / D_);
    float inv = rsqrtf(var + 1e-5f);
    float* orow = out + (size_t)row * D_;
    orow[lid]      = d0 * inv * g[lid] + b[lid];
    orow[lid + 64] = d1 * inv * g[lid + 64] + b[lid + 64];
}

// ---------------- weight transpose + bf16 hi/lo split (qkv, proj) ----------------
__global__ void tsplit(const float* __restrict__ W, unsigned short* __restrict__ Th,
                       unsigned short* __restrict__ Tl, int K, int N) {
    size_t zo = (size_t)blockIdx.z * K * N;
    __shared__ float t[32][33];
    int n0 = blockIdx.x * 32, k0 = blockIdx.y * 32;
    int c = threadIdx.x & 31, r0 = threadIdx.x >> 5;
#pragma unroll
    for (int i = 0; i < 4; i++) {
        int r = r0 + i * 8;
        t[r][c] = W[zo + (size_t)(k0 + r) * N + n0 + c];
    }
    __syncthreads();
#pragma unroll
    for (int i = 0; i < 4; i++) {
        int r = r0 + i * 8;
        float v = t[c][r];
        unsigned short h = f2bf(v);
        unsigned short l = f2bf(v - bf2f(h));
        Th[zo + (size_t)(n0 + r) * K + k0 + c] = h;
        Tl[zo + (size_t)(n0 + r) * K + k0 + c] = l;
    }
}

// ---------------- W1 prep: transpose + split + PRE-SWIZZLED k layout ----------------
__global__ void prep_w1(const float* __restrict__ W, unsigned short* __restrict__ Th,
                        unsigned short* __restrict__ Tl) {
    size_t zo = (size_t)blockIdx.z * 128 * 4096;
    size_t zo2 = (size_t)blockIdx.z * 4096 * 128;
    __shared__ float t[32][33];
    int n0 = blockIdx.x * 32, k0 = blockIdx.y * 32;
    int c = threadIdx.x & 31, r0 = threadIdx.x >> 5;
#pragma unroll
    for (int i = 0; i < 4; i++) {
        int r = r0 + i * 8;
        t[r][c] = W[zo + (size_t)(k0 + r) * 4096 + n0 + c];
    }
    __syncthreads();
#pragma unroll
    for (int i = 0; i < 4; i++) {
        int r = r0 + i * 8;
        int h = n0 + r;
        float v = t[c][r];
        unsigned short hh = f2bf(v);
        unsigned short ll = f2bf(v - bf2f(hh));
        int kk = (k0 + c) ^ ((h & 7) << 3);
        Th[zo2 + (size_t)h * 128 + kk] = hh;
        Tl[zo2 + (size_t)h * 128 + kk] = ll;
    }
}

// ---------------- W2 prep: split + kappa-permuted layout ----------------
// kappa(qh,j) = qh*4 + (j&3) + 16*(j>>2). Matches GEMM1-output A-frag k-order.
__global__ void prep_w2(const float* __restrict__ W, unsigned short* __restrict__ Th,
                        unsigned short* __restrict__ Tl) {
    size_t zo = (size_t)blockIdx.z * 4096 * 128;
    int e = blockIdx.x * 256 + threadIdx.x;
    int h = e >> 7, d = e & 127;
    float v = W[zo + (size_t)h * 128 + d];
    unsigned short hh = f2bf(v);
    unsigned short ll = f2bf(v - bf2f(hh));
    int cch = h >> 5, loc = h & 31;
    int qh = (loc & 15) >> 2;
    int j = (loc & 3) + ((loc >> 4) << 2);
    size_t off = zo + (size_t)cch * 4096 + qh * 1024 + d * 8 + j;
    Th[off] = hh;
    Tl[off] = ll;
}

// ---------------- split-bf16 MFMA GEMM: C = A(Mx128) @ B(128xNc) [+bias] [+resid] ----
template <bool BIAS, bool RESID>
__global__ __launch_bounds__(256) void gemm_mfma(
    const float* __restrict__ A, const unsigned short* __restrict__ BTh,
    const unsigned short* __restrict__ BTl, const float* __restrict__ bias,
    const float* __restrict__ resid, float* __restrict__ C, int Nc) {
    __shared__ __align__(16) char Ah[16384], Al[16384], Bh[16384], Bl[16384];
    int tid = threadIdx.x;
    int bN = blockIdx.x * 64, bM = blockIdx.y * 64;
#pragma unroll
    for (int i = 0; i < 8; i++) {
        int f = tid + i * 256;
        int row = f >> 5, k0 = (f & 31) * 4;
        int gm = bM + row;
        float4 v = make_float4(0.f, 0.f, 0.f, 0.f);
        if (gm < M_) v = *(const float4*)(A + (size_t)gm * 128 + k0);
        float vv[4] = {v.x, v.y, v.z, v.w};
        unsigned short h[4], l[4];
#pragma unroll
        for (int j = 0; j < 4; j++) { h[j] = f2bf(vv[j]); l[j] = f2bf(vv[j] - bf2f(h[j])); }
        int off = swz256(row, k0 * 2);
        *(short4v*)(Ah + off) = (short4v){(short)h[0], (short)h[1], (short)h[2], (short)h[3]};
        *(short4v*)(Al + off) = (short4v){(short)l[0], (short)l[1], (short)l[2], (short)l[3]};
    }
#pragma unroll
    for (int i = 0; i < 4; i++) {
        int c = tid + i * 256;
        int n = c >> 4, k0 = (c & 15) * 8;
        int off = swz256(n, k0 * 2);
        *(short8*)(Bh + off) = *(const short8*)(BTh + (size_t)(bN + n) * 128 + k0);
        *(short8*)(Bl + off) = *(const short8*)(BTl + (size_t)(bN + n) * 128 + k0);
    }
    __syncthreads();

    int lane = tid & 63, w = tid >> 6;
    int ln = lane & 15, qh = lane >> 4;
    int wr = w >> 1, wc = w & 1;
    f32x4 acc[2][2] = {};
#pragma unroll
    for (int ks = 0; ks < 4; ks++) {
        int kb = ks * 64 + qh * 16;
        short8 a_h[2], a_l[2], b_h[2], b_l[2];
#pragma unroll
        for (int rt = 0; rt < 2; rt++) {
            int r = wr * 32 + rt * 16 + ln;
            a_h[rt] = *(short8*)(Ah + swz256(r, kb));
            a_l[rt] = *(short8*)(Al + swz256(r, kb));
        }
#pragma unroll
        for (int ct = 0; ct < 2; ct++) {
            int n = wc * 32 + ct * 16 + ln;
            b_h[ct] = *(short8*)(Bh + swz256(n, kb));
            b_l[ct] = *(short8*)(Bl + swz256(n, kb));
        }
#pragma unroll
        for (int rt = 0; rt < 2; rt++)
#pragma unroll
            for (int ct = 0; ct < 2; ct++) {
                acc[rt][ct] = __builtin_amdgcn_mfma_f32_16x16x32_bf16(a_h[rt], b_h[ct], acc[rt][ct], 0, 0, 0);
                acc[rt][ct] = __builtin_amdgcn_mfma_f32_16x16x32_bf16(a_h[rt], b_l[ct], acc[rt][ct], 0, 0, 0);
                acc[rt][ct] = __builtin_amdgcn_mfma_f32_16x16x32_bf16(a_l[rt], b_h[ct], acc[rt][ct], 0, 0, 0);
            }
    }
#pragma unroll
    for (int rt = 0; rt < 2; rt++)
#pragma unroll
        for (int ct = 0; ct < 2; ct++) {
            int col = bN + wc * 32 + ct * 16 + ln;
            int row0 = bM + wr * 32 + rt * 16 + qh * 4;
            float bi = BIAS ? bias[col] : 0.0f;
#pragma unroll
            for (int r = 0; r < 4; r++) {
                int row = row0 + r;
                if (row < M_) {
                    float v = acc[rt][ct][r] + bi;
                    if (RESID) v += resid[(size_t)row * Nc + col];
                    C[(size_t)row * Nc + col] = v;
                }
            }
        }
}

// ---------------- MFMA flash attention ----------------
// grid (10, 64): y = b*8+h, x = 64-row q-tile; 4 waves x 16 q-rows.
// Split-bf16 via k-slot packing: head_dim=16 -> slots [0,16) = hi plane, [16,32) = lo.
// QK^T: mfma([Kh|Kl],[Qh|Qh]) + mfma([Kh|Kh],[Ql|0]) = K*Qh + Kh*Ql  (2 mfma)
// S^T layout: lane holds s[r] for q=lane&15, c=ct*16+(lane>>4)*4+r -> softmax state
// per-lane (q-indexed), row-max via 2 shuffles, O-rescale = 4 mults, NO reduce epilogue.
// PV: mfma([Vh|Vl],[Ph|Ph]) + mfma([Vh|Vh],[Pl|0]) = V*Ph + Vh*Pl  (2 mfma).
// K packed (hi<<16|lo) u32 [128][20]; V transposed u32 [16][132] (uniform-bank b128).
// Chunk-uniform mask skip (chunk 4 always active); c>=125 masked to -inf / zeroed V.
__global__ __launch_bounds__(256) void attn_mfma(const float* __restrict__ qkv,
                                                 const int* __restrict__ mask,
                                                 float* __restrict__ o) {
    __shared__ __align__(16) unsigned int Kp[128][20];
    __shared__ __align__(16) unsigned int Vp[16][132];
    int tid = threadIdx.x;
    int lane = tid & 63, w = tid >> 6;
    int ln = lane & 15, qh = lane >> 4;
    int bh = blockIdx.y;
    int b = bh >> 3, h = bh & 7;
    int mbase = blockIdx.x * 64;

    const float* base = qkv + (size_t)b * N_ * 384;
    // Q fragments (q pre-scaled; slots j<4 = hi, j>=4 = hi-dup / lo|0)
    short8 Bqh, Bql;
    {
        int qrow = min(mbase + w * 16 + ln, N_ - 1);
        float4 f = *(const float4*)(base + (size_t)qrow * 384 + h * HD_ + qh * 4);
        float ff[4] = {f.x * SCALE_, f.y * SCALE_, f.z * SCALE_, f.w * SCALE_};
        short hs[4], ls[4];
#pragma unroll
        for (int j = 0; j < 4; j++) {
            unsigned short hh = f2bf(ff[j]);
            hs[j] = (short)hh;
            ls[j] = (short)f2bf(ff[j] - bf2f(hh));
        }
        Bqh = (short8){hs[0], hs[1], hs[2], hs[3], hs[0], hs[1], hs[2], hs[3]};
        Bql = (short8){ls[0], ls[1], ls[2], ls[3], 0, 0, 0, 0};
    }
    // zero V pad cols 125..127 (never overwritten by staging; guards 0*NaN in PV)
    if (tid < 48) {
        int d = tid & 15, c = 125 + (tid >> 4);
        Vp[d][c] = 0;
    }

    float m = -3.4e38f, lsum = 0.f;
    f32x4 oacc = {0.f, 0.f, 0.f, 0.f};
    const int* mk = mask + b * 4;

    for (int ci = 0; ci < 5; ci++) {
        bool active = (ci == 4) || (mk[ci] != 0);  // block-uniform
        if (!active) continue;
        __syncthreads();   // prior chunk's LDS readers done (and pad-zero writes visible)
        const float* kc = base + (size_t)ci * 125 * 384 + 128 + h * HD_;
        const float* vc = kc + 128;
        for (int e = tid; e < 500; e += 256) {
            int c = e >> 2, dq = e & 3;
            float4 kf = *(const float4*)(kc + (size_t)c * 384 + dq * 4);
            float4 vf = *(const float4*)(vc + (size_t)c * 384 + dq * 4);
            float kk[4] = {kf.x, kf.y, kf.z, kf.w};
            float vv[4] = {vf.x, vf.y, vf.z, vf.w};
            unsigned int ku[4], vu[4];
#pragma unroll
            for (int j = 0; j < 4; j++) {
                unsigned short kh = f2bf(kk[j]);
                unsigned short kl = f2bf(kk[j] - bf2f(kh));
                ku[j] = ((unsigned)kh << 16) | (unsigned)kl;
                unsigned short vh = f2bf(vv[j]);
                unsigned short vl = f2bf(vv[j] - bf2f(vh));
                vu[j] = ((unsigned)vh << 16) | (unsigned)vl;
            }
            *(uint4*)&Kp[c][dq * 4] = make_uint4(ku[0], ku[1], ku[2], ku[3]);
            Vp[dq * 4 + 0][c] = vu[0];
            Vp[dq * 4 + 1][c] = vu[1];
            Vp[dq * 4 + 2][c] = vu[2];
            Vp[dq * 4 + 3][c] = vu[3];
        }
        __syncthreads();

#pragma unroll
        for (int ct = 0; ct < 8; ct++) {
            // ---- QK^T tile ----
            short8 aKf, aKd;
            unpack_fd(*(const uint4*)&Kp[ct * 16 + ln][qh * 4], &aKf, &aKd);
            f32x4 s = {0.f, 0.f, 0.f, 0.f};
            s = __builtin_amdgcn_mfma_f32_16x16x32_bf16(aKf, Bqh, s, 0, 0, 0);
            s = __builtin_amdgcn_mfma_f32_16x16x32_bf16(aKd, Bql, s, 0, 0, 0);
            if (ct == 7 && qh == 3) { s[1] = -INFINITY; s[2] = -INFINITY; s[3] = -INFINITY; }
            // ---- online softmax (state per q = ln) ----
            float tmax = fmaxf(fmaxf(s[0], s[1]), fmaxf(s[2], s[3]));
            tmax = fmaxf(tmax, __shfl_xor(tmax, 16, 64));
            tmax = fmaxf(tmax, __shfl_xor(tmax, 32, 64));
            float mnew = fmaxf(m, tmax);
            float sc = __expf(m - mnew);
            m = mnew;
            lsum *= sc;
            oacc[0] *= sc; oacc[1] *= sc; oacc[2] *= sc; oacc[3] *= sc;
            float p0 = __expf(s[0] - m), p1 = __expf(s[1] - m);
            float p2 = __expf(s[2] - m), p3 = __expf(s[3] - m);
            lsum += p0 + p1 + p2 + p3;
            unsigned short h0 = f2bf(p0), h1 = f2bf(p1), h2 = f2bf(p2), h3 = f2bf(p3);
            short8 Bph = (short8){(short)h0, (short)h1, (short)h2, (short)h3,
                                  (short)h0, (short)h1, (short)h2, (short)h3};
            short8 Bpl = (short8){(short)f2bf(p0 - bf2f(h0)), (short)f2bf(p1 - bf2f(h1)),
                                  (short)f2bf(p2 - bf2f(h2)), (short)f2bf(p3 - bf2f(h3)),
                                  0, 0, 0, 0};
            // ---- PV tile ----
            short8 aVf, aVd;
            unpack_fd(*(const uint4*)&Vp[ln][ct * 16 + qh * 4], &aVf, &aVd);
            oacc = __builtin_amdgcn_mfma_f32_16x16x32_bf16(aVf, Bph, oacc, 0, 0, 0);
            oacc = __builtin_amdgcn_mfma_f32_16x16x32_bf16(aVd, Bpl, oacc, 0, 0, 0);
        }
    }

    lsum += __shfl_xor(lsum, 16, 64);
    lsum += __shfl_xor(lsum, 32, 64);
    int orow = mbase + w * 16 + ln;
    if (orow < N_) {
        float inv = 1.0f / lsum;
        float4 r = make_float4(oacc[0] * inv, oacc[1] * inv, oacc[2] * inv, oacc[3] * inv);
        *(float4*)(o + (size_t)(b * N_ + orow) * D_ + h * HD_ + qh * 4) = r;
    }
}

// ---------------- out = resid + b2 (pre-init for MLP atomic accumulation) ----------------
__global__ void init_out(const float* __restrict__ resid, const float* __restrict__ b2,
                         float* __restrict__ dest) {
    int idx = blockIdx.x * 256 + threadIdx.x;
    if (idx < M_ * D_) dest[idx] = resid[idx] + b2[idx & 127];
}

// ---------------- fused MLP v3: reg-resident P + T3 double-buffer prefetch ----------------
__global__ __launch_bounds__(256, 2) void mlp_mfma3(
    const float* __restrict__ H2, const unsigned short* __restrict__ W1sh,
    const unsigned short* __restrict__ W1sl, const float* __restrict__ b1f,
    const unsigned short* __restrict__ W2kh, const unsigned short* __restrict__ W2kl,
    float* __restrict__ dest) {
    __shared__ __align__(16) char smem[66560];  // [0,32K) buf0, [32K,64K) buf1, [64K,+1K) b1f
    int tid = threadIdx.x;
    int slice = blockIdx.x & 15;
    int mt = blockIdx.x >> 4;
    int jb = slice * 256;
    int mbase = mt * 64;
    int lane = tid & 63, w = tid >> 6;
    int ln = lane & 15, qh = lane >> 4;

    const char* pb;
    if (w == 0)      pb = (const char*)W1sh + (size_t)jb * 256;
    else if (w == 1) pb = (const char*)W1sl + (size_t)jb * 256;
    else if (w == 2) pb = (const char*)W2kh + (size_t)slice * 65536;
    else             pb = (const char*)W2kl + (size_t)slice * 65536;

    int t = min(mbase + w * 16 + ln, M_ - 1);
    short8 hfh[4], hfl[4];
    {
        const float* hp = H2 + (size_t)t * 128 + qh * 8;
#pragma unroll
        for (int ks = 0; ks < 4; ks++) {
            float4 v0 = *(const float4*)(hp + ks * 32);
            float4 v1 = *(const float4*)(hp + ks * 32 + 4);
            float vv[8] = {v0.x, v0.y, v0.z, v0.w, v1.x, v1.y, v1.z, v1.w};
            short8 sh, sl;
#pragma unroll
            for (int j = 0; j < 8; j++) {
                unsigned short hh = f2bf(vv[j]);
                sh[j] = (short)hh;
                sl[j] = (short)f2bf(vv[j] - bf2f(hh));
            }
            hfh[ks] = sh; hfl[ks] = sl;
        }
    }

    {
        char* lb = smem + w * 8192;
#pragma unroll
        for (int c = 0; c < 8; c++) gll16(pb + c * 1024 + lane * 16, lb + c * 1024);
        ((float*)(smem + 65536))[tid] = b1f[jb + tid];
    }
    __syncthreads();

    const float* bls = (const float*)(smem + 65536);
    f32x4 acc2[8] = {};

    for (int it = 0; it < 8; it++) {
        char* buf = smem + (it & 1) * 32768;
        if (it < 7) {
            char* lb = smem + ((it + 1) & 1) * 32768 + w * 8192;
            const char* gb = pb + (size_t)(it + 1) * 8192;
#pragma unroll
            for (int c = 0; c < 8; c++) gll16(gb + c * 1024 + lane * 16, lb + c * 1024);
        }
        f32x4 p[2] = {};
#pragma unroll
        for (int ht = 0; ht < 2; ht++)
#pragma unroll
            for (int ks = 0; ks < 4; ks++) {
                int row = ht * 16 + ln;
                int kb = ks * 64 + qh * 16;
                short8 ah = *(short8*)(buf + swz256(row, kb));
                short8 al = *(short8*)(buf + 8192 + swz256(row, kb));
                p[ht] = __builtin_amdgcn_mfma_f32_16x16x32_bf16(ah, hfh[ks], p[ht], 0, 0, 0);
                p[ht] = __builtin_amdgcn_mfma_f32_16x16x32_bf16(ah, hfl[ks], p[ht], 0, 0, 0);
                p[ht] = __builtin_amdgcn_mfma_f32_16x16x32_bf16(al, hfh[ks], p[ht], 0, 0, 0);
            }
        short8 pah, pal;
#pragma unroll
        for (int ht = 0; ht < 2; ht++)
#pragma unroll
            for (int r = 0; r < 4; r++) {
                float bi = bls[it * 32 + ht * 16 + qh * 4 + r];
                float v = p[ht][r] + bi;
                float g = gelu_fast(v);
                unsigned short gh = f2bf(g);
                pah[ht * 4 + r] = (short)gh;
                pal[ht * 4 + r] = (short)f2bf(g - bf2f(gh));
            }
#pragma unroll
        for (int dt = 0; dt < 8; dt++) {
            int off = 16384 + qh * 2048 + (dt * 16 + ln) * 16;
            short8 bh = *(short8*)(buf + off);
            short8 bl = *(short8*)(buf + off + 8192);
            acc2[dt] = __builtin_amdgcn_mfma_f32_16x16x32_bf16(pah, bh, acc2[dt], 0, 0, 0);
            acc2[dt] = __builtin_amdgcn_mfma_f32_16x16x32_bf16(pah, bl, acc2[dt], 0, 0, 0);
            acc2[dt] = __builtin_amdgcn_mfma_f32_16x16x32_bf16(pal, bh, acc2[dt], 0, 0, 0);
        }
        __syncthreads();
    }

    int trow = mbase + w * 16 + qh * 4;
#pragma unroll
    for (int dt = 0; dt < 8; dt++) {
        int d = dt * 16 + ln;
#pragma unroll
        for (int r = 0; r < 4; r++) {
            int row = trow + r;
            if (row < M_) atomicAdd(dest + (size_t)row * 128 + d, acc2[dt][r]);
        }
    }
}

extern "C" void kernel_launch(void* const* d_in, const int* in_sizes, int n_in,
                              void* d_out, int out_size, void* d_ws, size_t ws_size,
                              hipStream_t stream) {
    const float* x     = (const float*)d_in[0];
    const int*   mask  = (const int*)d_in[1];
    const float* Wqkv  = (const float*)d_in[2];
    const float* Wproj = (const float*)d_in[3];
    const float* bproj = (const float*)d_in[4];
    const float* g1    = (const float*)d_in[5];
    const float* b1    = (const float*)d_in[6];
    const float* g2    = (const float*)d_in[7];
    const float* b2    = (const float*)d_in[8];
    const float* W1f   = (const float*)d_in[9];
    const float* b1f   = (const float*)d_in[10];
    const float* W2f   = (const float*)d_in[11];
    const float* b2f   = (const float*)d_in[12];
    float* out = (float*)d_out;
    float* ws = (float*)d_ws;

    float* xbuf   = ws;                 // 640000 f
    float* hbuf   = ws + 640000;
    float* qkvbuf = ws + 1280000;       // 1920000 f
    float* obuf   = ws + 3200000;       // 640000 f
    unsigned short* qh  = (unsigned short*)(ws + 3840000);
    unsigned short* ql  = qh + 3 * 384 * 128;
    unsigned short* phw = ql + 3 * 384 * 128;
    unsigned short* plw = phw + 3 * 128 * 128;
    unsigned short* w1h = plw + 3 * 128 * 128;   // pre-swizzled [h][k]
    unsigned short* w1l = w1h + 3 * 4096 * 128;
    unsigned short* w2h = w1l + 3 * 4096 * 128;  // kappa layout [c][qh][d][j]
    unsigned short* w2l = w2h + 3 * 128 * 4096;

    tsplit<<<dim3(12, 4, 3), 256, 0, stream>>>(Wqkv, qh, ql, 128, 384);
    tsplit<<<dim3(4, 4, 3), 256, 0, stream>>>(Wproj, phw, plw, 128, 128);
    prep_w1<<<dim3(128, 4, 3), 256, 0, stream>>>(W1f, w1h, w1l);
    prep_w2<<<dim3(2048, 1, 3), 256, 0, stream>>>(W2f, w2h, w2l);

    for (int l = 0; l < 3; l++) {
        const float* xcur = (l == 0) ? x : xbuf;
        ln_kernel<<<1250, 256, 0, stream>>>(xcur, g1 + l * D_, b1 + l * D_, hbuf);
        gemm_mfma<false, false><<<dim3(6, 79), 256, 0, stream>>>(
            hbuf, qh + (size_t)l * 384 * 128, ql + (size_t)l * 384 * 128,
            nullptr, nullptr, qkvbuf, 384);
        attn_mfma<<<dim3(10, 64), 256, 0, stream>>>(qkvbuf, mask, obuf);
        gemm_mfma<true, true><<<dim3(2, 79), 256, 0, stream>>>(
            obuf, phw + (size_t)l * 128 * 128, plw + (size_t)l * 128 * 128,
            bproj + l * D_, xcur, xbuf, 128);
        ln_kernel<<<1250, 256, 0, stream>>>(xbuf, g2 + l * D_, b2 + l * D_, hbuf);
        float* dest = (l == 2) ? out : xbuf;
        init_out<<<2500, 256, 0, stream>>>(xbuf, b2f + l * D_, dest);
        mlp_mfma3<<<1264, 256, 0, stream>>>(
            hbuf, w1h + (size_t)l * 4096 * 128, w1l + (size_t)l * 4096 * 128,
            b1f + (size_t)l * MLP_,
            w2h + (size_t)l * 128 * 4096, w2l + (size_t)l * 128 * 4096, dest);
    }
}